// Round 6
// baseline (310.720 us; speedup 1.0000x reference)
//
#include <hip/hip_runtime.h>
#include <hip/hip_bf16.h>
#include <stdint.h>

typedef __bf16 bf16;
typedef __bf16 bf16x4 __attribute__((ext_vector_type(4)));
typedef __bf16 bf16x8 __attribute__((ext_vector_type(8)));
typedef float f32x4 __attribute__((ext_vector_type(4)));

// async global->LDS, 16B per lane. LDS dest is wave-uniform base + lane*16.
__device__ __forceinline__ void async_ld16(const void* g, void* l) {
  __builtin_amdgcn_global_load_lds(
      (__attribute__((address_space(1))) void*)(void*)(g),
      (__attribute__((address_space(3))) void*)(l), 16, 0, 0);
}

// fast f32->bf16 (round-half-up): 2 VALU ops. Values are finite, non-NaN.
__device__ __forceinline__ bf16 fast_bf16(float f) {
  uint32_t u = (__float_as_uint(f) + 0x8000u) >> 16;
  union { uint16_t s; bf16 b; } cv;
  cv.s = (uint16_t)u;
  return cv.b;
}

// pack two f32 -> bf16x2 in a u32: 2 adds + 1 v_perm_b32.
__device__ __forceinline__ uint32_t pack_bf16(float lo, float hi) {
  return __builtin_amdgcn_perm(__float_as_uint(hi) + 0x8000u,
                               __float_as_uint(lo) + 0x8000u, 0x07060302u);
}

// ---------------- cast x fp32 -> bf16 ----------------
__global__ __launch_bounds__(256) void cast_f32_bf16(const float* __restrict__ in,
                                                     bf16* __restrict__ out, int n) {
  int i = (blockIdx.x * 256 + threadIdx.x) * 4;
  if (i < n) {
    float4 f = *(const float4*)(in + i);
    uint2 o;
    o.x = pack_bf16(f.x, f.y);
    o.y = pack_bf16(f.z, f.w);
    *(uint2*)(out + i) = o;
  }
}

// ---------------- fused weight transpose-cast: Wq/Wk/Wv -> Wt, Wo -> Wot ----------------
__global__ __launch_bounds__(256) void transpose_weights(const float* __restrict__ Wq,
                                                         const float* __restrict__ Wk,
                                                         const float* __restrict__ Wv,
                                                         const float* __restrict__ Wo,
                                                         bf16* __restrict__ Wt,
                                                         bf16* __restrict__ Wot) {
  __shared__ bf16 tile[64][66];
  int z = blockIdx.z;
  const float* src = z == 0 ? Wq : (z == 1 ? Wk : (z == 2 ? Wv : Wo));
  bf16* dst = z == 0 ? Wt : (z == 1 ? Wt + 1048576 : (z == 2 ? Wt + 2097152 : Wot));
  int r0 = blockIdx.x * 64, c0 = blockIdx.y * 64;
  int t = threadIdx.x;
#pragma unroll
  for (int i = 0; i < 16; ++i) {
    int idx = t + i * 256;
    int r = idx >> 6, c = idx & 63;
    tile[r][c] = fast_bf16(src[(size_t)(r0 + r) * 1024 + (c0 + c)]);
  }
  __syncthreads();
#pragma unroll
  for (int i = 0; i < 16; ++i) {
    int idx = t + i * 256;
    int c = idx >> 6, r = idx & 63;
    dst[(size_t)(c0 + c) * 1024 + (r0 + r)] = tile[r][c];
  }
}

// ---------------- 128x128 bf16 GEMM mainloop, XOR-swizzled LDS ----------------
// LDS layout: 16B chunk c of row r stored at chunk position c^(r&7).
// All fragment reads use rows == l15 (mod 8), so reads are conflict-free.
__device__ __forceinline__ void gemm128_mainloop(const bf16* __restrict__ A,
                                                 const bf16* __restrict__ Bt, int K,
                                                 int rowBase, int colBase,
                                                 bf16* As, bf16* Bs,
                                                 f32x4 (&acc)[4][4]) {
  int t = threadIdx.x, lane = t & 63, w = t >> 6;
  int wM = w >> 1, wN = w & 1, quad = lane >> 4, l15 = lane & 15;
  int r_off = lane >> 3;
  int c_sw = (((lane & 7) ^ r_off) << 3);  // swizzled source column (elements)
  int sw = l15 & 7;
  for (int k0 = 0; k0 < K; k0 += 64) {
    __syncthreads();  // previous tile's compute reads done
#pragma unroll
    for (int i = 0; i < 4; ++i) {
      int e = i * 2048 + w * 512;          // wave-uniform LDS segment (elements)
      int row = (e >> 6) + r_off;
      async_ld16(A + (size_t)(rowBase + row) * K + (k0 + c_sw), As + e);
      async_ld16(Bt + (size_t)(colBase + row) * K + (k0 + c_sw), Bs + e);
    }
    __syncthreads();  // drains vmcnt -> staged data visible
#pragma unroll
    for (int ks = 0; ks < 2; ++ks) {
      int co = (((ks * 4 + quad) ^ sw) << 3);
      bf16x8 af[4], bfr[4];
#pragma unroll
      for (int mi = 0; mi < 4; ++mi)
        af[mi] = *(const bf16x8*)(As + (wM * 64 + mi * 16 + l15) * 64 + co);
#pragma unroll
      for (int ni = 0; ni < 4; ++ni)
        bfr[ni] = *(const bf16x8*)(Bs + (wN * 64 + ni * 16 + l15) * 64 + co);
#pragma unroll
      for (int mi = 0; mi < 4; ++mi)
#pragma unroll
        for (int ni = 0; ni < 4; ++ni)
          acc[mi][ni] = __builtin_amdgcn_mfma_f32_16x16x32_bf16(af[mi], bfr[ni], acc[mi][ni], 0, 0, 0);
    }
  }
}

// GEMM1: X[8192,1024] @ Wqkv^T[3072,1024] -> Q [bh][s][d] (scaled by log2e/8),
// K [bh][s][d], V^T [bh][d][s] bf16. V^T goes through an LDS re-tile so global
// stores are coalesced b128 (direct stores were 8B/lane at 4KB stride).
__global__ __launch_bounds__(256) void gemm_qkv(const bf16* __restrict__ X,
                                                const bf16* __restrict__ Wt,
                                                const float* __restrict__ bq,
                                                const float* __restrict__ bk,
                                                const float* __restrict__ bv,
                                                bf16* __restrict__ Qo,
                                                bf16* __restrict__ Ko,
                                                bf16* __restrict__ Vto) {
  __shared__ alignas(16) bf16 smem[2 * 128 * 64];  // As|Bs; V-epilogue reuses as [64][136]
  bf16* As = smem;
  bf16* Bs = smem + 128 * 64;
  f32x4 acc[4][4];
  f32x4 z = {0.f, 0.f, 0.f, 0.f};
#pragma unroll
  for (int mi = 0; mi < 4; ++mi)
#pragma unroll
    for (int ni = 0; ni < 4; ++ni) acc[mi][ni] = z;
  int rowBase = blockIdx.x * 128, colBase = blockIdx.y * 128;
  gemm128_mainloop(X, Wt, 1024, rowBase, colBase, As, Bs, acc);

  int t = threadIdx.x, lane = t & 63, w = t >> 6;
  int wM = w >> 1, wN = w & 1, quad = lane >> 4, l15 = lane & 15;
  int which = colBase >> 10;  // 0:q 1:k 2:v (128-tiles never straddle)

  if (which == 2) {
    // V^T [bh][d][s]: LDS re-tile per 64-col half, then coalesced b128 stores.
    int baseh = (colBase & 1023) >> 6;
    int b = rowBase >> 11, s0 = rowBase & 2047;
#pragma unroll
    for (int hp = 0; hp < 2; ++hp) {
      __syncthreads();  // smem free (mainloop or previous pass reads done)
      if (wN == hp) {
#pragma unroll
        for (int mi = 0; mi < 4; ++mi)
#pragma unroll
          for (int ni = 0; ni < 4; ++ni) {
            int d = ni * 16 + l15;
            float bb = bv[(colBase & 1023) + hp * 64 + d];
            int sl = wM * 64 + mi * 16 + quad * 4;
            uint2 pv;
            pv.x = pack_bf16(acc[mi][ni][0] + bb, acc[mi][ni][1] + bb);
            pv.y = pack_bf16(acc[mi][ni][2] + bb, acc[mi][ni][3] + bb);
            *(uint2*)(smem + d * 136 + sl) = pv;
          }
      }
      __syncthreads();  // tile [64 d][128 s] staged
      int hg = baseh + hp;
#pragma unroll
      for (int it = 0; it < 4; ++it) {
        int idx = t + it * 256;
        int d = idx >> 4, c = idx & 15;
        bf16x8 vv = *(const bf16x8*)(smem + d * 136 + c * 8);
        *(bf16x8*)(Vto + (((size_t)((b << 4) + hg) << 6) + d) * 2048 + s0 + c * 8) = vv;
      }
    }
  } else {
    const float* bias = which == 0 ? bq : bk;
    bf16* dst = which == 0 ? Qo : Ko;
    float scale = which == 0 ? 0.125f * 1.44269504f : 1.0f;
#pragma unroll
    for (int mi = 0; mi < 4; ++mi)
#pragma unroll
      for (int ni = 0; ni < 4; ++ni) {
        int n = colBase + wN * 64 + ni * 16 + l15;
        int e = n & 1023;
        int h = e >> 6, d = e & 63;
        float bb = bias[e];
#pragma unroll
        for (int r = 0; r < 4; ++r) {
          int m = rowBase + wM * 64 + mi * 16 + quad * 4 + r;
          int b = m >> 11, s = m & 2047;
          dst[(((size_t)((b << 4) + h) * 2048 + s) << 6) + d] =
              fast_bf16((acc[mi][ni][r] + bb) * scale);
        }
      }
  }
}

// GEMM2: ctx[8192,1024] @ Wo^T[1024,1024] + bo -> out fp32
__global__ __launch_bounds__(256) void gemm_out(const bf16* __restrict__ Cb,
                                                const bf16* __restrict__ Wot,
                                                const float* __restrict__ bo,
                                                float* __restrict__ out) {
  __shared__ alignas(16) bf16 As[128 * 64];
  __shared__ alignas(16) bf16 Bs[128 * 64];
  f32x4 acc[4][4];
  f32x4 z = {0.f, 0.f, 0.f, 0.f};
#pragma unroll
  for (int mi = 0; mi < 4; ++mi)
#pragma unroll
    for (int ni = 0; ni < 4; ++ni) acc[mi][ni] = z;
  int rowBase = blockIdx.x * 128, colBase = blockIdx.y * 128;
  gemm128_mainloop(Cb, Wot, 1024, rowBase, colBase, As, Bs, acc);

  int t = threadIdx.x, lane = t & 63, w = t >> 6;
  int wM = w >> 1, wN = w & 1, quad = lane >> 4, l15 = lane & 15;
#pragma unroll
  for (int mi = 0; mi < 4; ++mi)
#pragma unroll
    for (int ni = 0; ni < 4; ++ni) {
      int n = colBase + wN * 64 + ni * 16 + l15;
      float bb = bo[n];
#pragma unroll
      for (int r = 0; r < 4; ++r) {
        int m = rowBase + wM * 64 + mi * 16 + quad * 4 + r;
        out[(size_t)m * 1024 + n] = acc[mi][ni][r] + bb;
      }
    }
}

// ---------------- flash attention: 256q blocks, 64q/wave, half-split P pipeline ----
// Q pre-scaled by log2(e)/8. Layouts: Q,K = [bh][S][64]; Vt = [bh][64][S]; ctx bf16.
// Per 64-key tile: S(keys 0-31) -> exp/P0 -> S(keys 32-63) -> PV0 MFMAs overlap
// exp(keys 32-63) -> PV1. l computed by ones-B-fragment MFMA (row-sum of P),
// landing per-lane in exactly the epilogue layout (no shuffles, no VALU adds).
// Q staged through the K/V dbuf region (dead after prologue): LDS = 48 KB.
__global__ __launch_bounds__(256, 2) void attn(const bf16* __restrict__ Q,
                                               const bf16* __restrict__ Kg,
                                               const bf16* __restrict__ Vt,
                                               bf16* __restrict__ ctx) {
  __shared__ alignas(16) bf16 KVs[4][4096];  // [K buf0, K buf1, V buf0, V buf1]; prologue: Q
  __shared__ alignas(16) bf16 Ps[4][2048];   // per-wave P half-tile (64q x 32k)

  int t = threadIdx.x, lane = t & 63, w = t >> 6;
  int quad = lane >> 4, l15 = lane & 15;
  int r_off = lane >> 3;
  int c_sw = (((lane & 7) ^ r_off) << 3);
  int sw = l15 & 7;
  int bh = blockIdx.y;
  int q0 = blockIdx.x * 256;
  const bf16* Qp = Q + ((size_t)bh * 2048 + q0) * 64;
  const bf16* Kp = Kg + (size_t)bh * 2048 * 64;
  const bf16* Vp = Vt + (size_t)bh * 64 * 2048;

  // prologue: wave w stages its own 64 Q rows into KVs[w] (swizzled)
#pragma unroll
  for (int i = 0; i < 8; ++i) {
    int e = i * 512;
    int row = i * 8 + r_off;
    async_ld16(Qp + (size_t)(w * 64 + row) * 64 + c_sw, KVs[w] + e);
  }
  __syncthreads();  // Q staged (barrier drains vmcnt)

  // Q B-fragments -> registers (8 x bf16x8 = 32 VGPRs)
  bf16x8 qf[2][4];
#pragma unroll
  for (int ks = 0; ks < 2; ++ks)
#pragma unroll
    for (int qi = 0; qi < 4; ++qi)
      qf[ks][qi] = *(const bf16x8*)(KVs[w] + (qi * 16 + l15) * 64 + (((ks * 4 + quad) ^ sw) << 3));
  __syncthreads();  // all qf reads done (barrier drains lgkm) -> KVs reusable

  // stage K/V tile 0 into buf 0
#pragma unroll
  for (int i = 0; i < 2; ++i) {
    int e = w * 1024 + i * 512;
    int row = (e >> 6) + r_off;
    async_ld16(Kp + (size_t)row * 64 + c_sw, KVs[0] + e);
    async_ld16(Vp + (size_t)row * 2048 + c_sw, KVs[2] + e);
  }

  bf16 one1 = (bf16)1.0f;
  bf16x8 ones = {one1, one1, one1, one1, one1, one1, one1, one1};
  bf16* Pw = Ps[w];

  f32x4 o[4][4];
  f32x4 ol[4];
  f32x4 z = {0.f, 0.f, 0.f, 0.f};
#pragma unroll
  for (int mi = 0; mi < 4; ++mi) {
    ol[mi] = z;
#pragma unroll
    for (int ni = 0; ni < 4; ++ni) o[mi][ni] = z;
  }

  for (int kt = 0; kt < 32; ++kt) {
    int cur = kt & 1;
    __syncthreads();  // buf[cur] deposits drained (vmcnt0 at barrier); old reads done
    // prefetch next tile into the other buffer (overlaps compute below)
    if (kt < 31) {
      int kn = (kt + 1) * 64;
#pragma unroll
      for (int i = 0; i < 2; ++i) {
        int e = w * 1024 + i * 512;
        int row = (e >> 6) + r_off;
        async_ld16(Kp + (size_t)(kn + row) * 64 + c_sw, KVs[cur ^ 1] + e);
        async_ld16(Vp + (size_t)row * 2048 + kn + c_sw, KVs[2 + (cur ^ 1)] + e);
      }
    }
    const bf16* Kc = KVs[cur];
    const bf16* Vc = KVs[2 + cur];

    // ---- S^T keys 0..31 (ki=0,1), both k-chunks ----
    f32x4 sA[2][4];
#pragma unroll
    for (int ki = 0; ki < 2; ++ki)
#pragma unroll
      for (int qi = 0; qi < 4; ++qi) sA[ki][qi] = z;
#pragma unroll
    for (int ks = 0; ks < 2; ++ks) {
      int co = (((ks * 4 + quad) ^ sw) << 3);
      bf16x8 kf0 = *(const bf16x8*)(Kc + (l15)*64 + co);
      bf16x8 kf1 = *(const bf16x8*)(Kc + (16 + l15) * 64 + co);
#pragma unroll
      for (int qi = 0; qi < 4; ++qi) {
        sA[0][qi] = __builtin_amdgcn_mfma_f32_16x16x32_bf16(kf0, qf[ks][qi], sA[0][qi], 0, 0, 0);
        sA[1][qi] = __builtin_amdgcn_mfma_f32_16x16x32_bf16(kf1, qf[ks][qi], sA[1][qi], 0, 0, 0);
      }
    }
    // exp + pack + write P0 (keys local 0..31)
#pragma unroll
    for (int qi = 0; qi < 4; ++qi)
#pragma unroll
      for (int ki = 0; ki < 2; ++ki) {
        float p0 = __builtin_amdgcn_exp2f(sA[ki][qi][0]);
        float p1 = __builtin_amdgcn_exp2f(sA[ki][qi][1]);
        float p2 = __builtin_amdgcn_exp2f(sA[ki][qi][2]);
        float p3 = __builtin_amdgcn_exp2f(sA[ki][qi][3]);
        uint2 pb;
        pb.x = pack_bf16(p0, p1);
        pb.y = pack_bf16(p2, p3);
        *(uint2*)(Pw + (qi * 16 + l15) * 32 + ki * 16 + quad * 4) = pb;
      }

    // ---- S^T keys 32..63 (ki=2,3) ----
    f32x4 sB[2][4];
#pragma unroll
    for (int ki = 0; ki < 2; ++ki)
#pragma unroll
      for (int qi = 0; qi < 4; ++qi) sB[ki][qi] = z;
#pragma unroll
    for (int ks = 0; ks < 2; ++ks) {
      int co = (((ks * 4 + quad) ^ sw) << 3);
      bf16x8 kf2 = *(const bf16x8*)(Kc + (32 + l15) * 64 + co);
      bf16x8 kf3 = *(const bf16x8*)(Kc + (48 + l15) * 64 + co);
#pragma unroll
      for (int qi = 0; qi < 4; ++qi) {
        sB[0][qi] = __builtin_amdgcn_mfma_f32_16x16x32_bf16(kf2, qf[ks][qi], sB[0][qi], 0, 0, 0);
        sB[1][qi] = __builtin_amdgcn_mfma_f32_16x16x32_bf16(kf3, qf[ks][qi], sB[1][qi], 0, 0, 0);
      }
    }

    asm volatile("s_waitcnt lgkmcnt(0)" ::: "memory");  // P0 visible

    // ---- PV half 0 (keys 0..31) + l row-sum; exp of half 1 overlaps these MFMAs ----
    {
      int co = ((quad ^ sw) << 3);  // ks=0
      bf16x8 pf[4], vf[4];
#pragma unroll
      for (int mi = 0; mi < 4; ++mi)
        pf[mi] = *(const bf16x8*)(Pw + (mi * 16 + l15) * 32 + quad * 8);
#pragma unroll
      for (int ni = 0; ni < 4; ++ni)
        vf[ni] = *(const bf16x8*)(Vc + (ni * 16 + l15) * 64 + co);
#pragma unroll
      for (int mi = 0; mi < 4; ++mi) {
#pragma unroll
        for (int ni = 0; ni < 4; ++ni)
          o[mi][ni] = __builtin_amdgcn_mfma_f32_16x16x32_bf16(pf[mi], vf[ni], o[mi][ni], 0, 0, 0);
        ol[mi] = __builtin_amdgcn_mfma_f32_16x16x32_bf16(pf[mi], ones, ol[mi], 0, 0, 0);
      }
    }

    // exp + pack + write P1 (keys local 32..63 -> P buffer offset 0..31)
#pragma unroll
    for (int qi = 0; qi < 4; ++qi)
#pragma unroll
      for (int ki = 0; ki < 2; ++ki) {
        float p0 = __builtin_amdgcn_exp2f(sB[ki][qi][0]);
        float p1 = __builtin_amdgcn_exp2f(sB[ki][qi][1]);
        float p2 = __builtin_amdgcn_exp2f(sB[ki][qi][2]);
        float p3 = __builtin_amdgcn_exp2f(sB[ki][qi][3]);
        uint2 pb;
        pb.x = pack_bf16(p0, p1);
        pb.y = pack_bf16(p2, p3);
        *(uint2*)(Pw + (qi * 16 + l15) * 32 + ki * 16 + quad * 4) = pb;
      }

    asm volatile("s_waitcnt lgkmcnt(0)" ::: "memory");  // P1 visible

    // ---- PV half 1 (keys 32..63) + l row-sum ----
    {
      int co = (((4 + quad) ^ sw) << 3);  // ks=1
      bf16x8 pf[4], vf[4];
#pragma unroll
      for (int mi = 0; mi < 4; ++mi)
        pf[mi] = *(const bf16x8*)(Pw + (mi * 16 + l15) * 32 + quad * 8);
#pragma unroll
      for (int ni = 0; ni < 4; ++ni)
        vf[ni] = *(const bf16x8*)(Vc + (ni * 16 + l15) * 64 + co);
#pragma unroll
      for (int mi = 0; mi < 4; ++mi) {
#pragma unroll
        for (int ni = 0; ni < 4; ++ni)
          o[mi][ni] = __builtin_amdgcn_mfma_f32_16x16x32_bf16(pf[mi], vf[ni], o[mi][ni], 0, 0, 0);
        ol[mi] = __builtin_amdgcn_mfma_f32_16x16x32_bf16(pf[mi], ones, ol[mi], 0, 0, 0);
      }
    }
  }

  // epilogue: ol[mi][r] = l for query mi*16+quad*4+r (uniform across l15) -> no shuffles
  int b = bh >> 4, h = bh & 15;
#pragma unroll
  for (int mi = 0; mi < 4; ++mi) {
    float rl[4];
#pragma unroll
    for (int r = 0; r < 4; ++r) rl[r] = 1.0f / ol[mi][r];
#pragma unroll
    for (int ni = 0; ni < 4; ++ni) {
      int col = h * 64 + ni * 16 + l15;
#pragma unroll
      for (int r = 0; r < 4; ++r) {
        int q = q0 + w * 64 + mi * 16 + quad * 4 + r;
        ctx[(size_t)(b * 2048 + q) * 1024 + col] = fast_bf16(o[mi][ni][r] * rl[r]);
      }
    }
  }
}

extern "C" void kernel_launch(void* const* d_in, const int* in_sizes, int n_in,
                              void* d_out, int out_size, void* d_ws, size_t ws_size,
                              hipStream_t stream) {
  const float* x  = (const float*)d_in[0];
  const float* Wq = (const float*)d_in[1];
  const float* bq = (const float*)d_in[2];
  const float* Wk = (const float*)d_in[3];
  const float* bk = (const float*)d_in[4];
  const float* Wv = (const float*)d_in[5];
  const float* bv = (const float*)d_in[6];
  const float* Wo = (const float*)d_in[7];
  const float* bo = (const float*)d_in[8];
  float* out = (float*)d_out;

  char* ws = (char*)d_ws;
  const size_t MB = 1048576;
  bf16* xb  = (bf16*)(ws);             // 16 MB: x bf16 [8192][1024]
  bf16* Wt  = (bf16*)(ws + 16 * MB);   //  6 MB: Wqkv^T [3072][1024]
  bf16* Wot = (bf16*)(ws + 22 * MB);   //  2 MB: Wo^T   [1024][1024]
  bf16* Qb  = (bf16*)(ws + 24 * MB);   // 16 MB: Q [64][2048][64] (pre-scaled by log2e/8)
  bf16* Kb  = (bf16*)(ws + 40 * MB);   // 16 MB: K [64][2048][64]
  bf16* Vtb = (bf16*)(ws + 56 * MB);   // 16 MB: V^T [64][64][2048]
  bf16* Cx  = (bf16*)(ws + 72 * MB);   // 16 MB: ctx [8192][1024]

  cast_f32_bf16<<<8192, 256, 0, stream>>>(x, xb, 8388608);
  transpose_weights<<<dim3(16, 16, 4), 256, 0, stream>>>(Wq, Wk, Wv, Wo, Wt, Wot);
  gemm_qkv<<<dim3(64, 24, 1), 256, 0, stream>>>(xb, Wt, bq, bk, bv, Qb, Kb, Vtb);
  attn<<<dim3(8, 64, 1), 256, 0, stream>>>(Qb, Kb, Vtb, Cx);
  gemm_out<<<dim3(64, 8, 1), 256, 0, stream>>>(Cx, Wot, bo, out);
}

// Round 7
// 276.247 us; speedup vs baseline: 1.1248x; 1.1248x over previous
//
#include <hip/hip_runtime.h>
#include <hip/hip_bf16.h>
#include <stdint.h>

typedef __bf16 bf16;
typedef __bf16 bf16x4 __attribute__((ext_vector_type(4)));
typedef __bf16 bf16x8 __attribute__((ext_vector_type(8)));
typedef float f32x4 __attribute__((ext_vector_type(4)));

// async global->LDS, 16B per lane. LDS dest is wave-uniform base + lane*16.
__device__ __forceinline__ void async_ld16(const void* g, void* l) {
  __builtin_amdgcn_global_load_lds(
      (__attribute__((address_space(1))) void*)(void*)(g),
      (__attribute__((address_space(3))) void*)(l), 16, 0, 0);
}

// fast f32->bf16 (round-half-up): 2 VALU ops. Values are finite, non-NaN.
__device__ __forceinline__ bf16 fast_bf16(float f) {
  uint32_t u = (__float_as_uint(f) + 0x8000u) >> 16;
  union { uint16_t s; bf16 b; } cv;
  cv.s = (uint16_t)u;
  return cv.b;
}

// pack two f32 -> bf16x2 in a u32: 2 adds + 1 v_perm_b32.
__device__ __forceinline__ uint32_t pack_bf16(float lo, float hi) {
  return __builtin_amdgcn_perm(__float_as_uint(hi) + 0x8000u,
                               __float_as_uint(lo) + 0x8000u, 0x07060302u);
}

// ---------------- cast x fp32 -> bf16 ----------------
__global__ __launch_bounds__(256) void cast_f32_bf16(const float* __restrict__ in,
                                                     bf16* __restrict__ out, int n) {
  int i = (blockIdx.x * 256 + threadIdx.x) * 4;
  if (i < n) {
    float4 f = *(const float4*)(in + i);
    uint2 o;
    o.x = pack_bf16(f.x, f.y);
    o.y = pack_bf16(f.z, f.w);
    *(uint2*)(out + i) = o;
  }
}

// ---------------- fused weight transpose-cast: Wq/Wk/Wv -> Wt, Wo -> Wot ----------------
__global__ __launch_bounds__(256) void transpose_weights(const float* __restrict__ Wq,
                                                         const float* __restrict__ Wk,
                                                         const float* __restrict__ Wv,
                                                         const float* __restrict__ Wo,
                                                         bf16* __restrict__ Wt,
                                                         bf16* __restrict__ Wot) {
  __shared__ bf16 tile[64][66];
  int z = blockIdx.z;
  const float* src = z == 0 ? Wq : (z == 1 ? Wk : (z == 2 ? Wv : Wo));
  bf16* dst = z == 0 ? Wt : (z == 1 ? Wt + 1048576 : (z == 2 ? Wt + 2097152 : Wot));
  int r0 = blockIdx.x * 64, c0 = blockIdx.y * 64;
  int t = threadIdx.x;
#pragma unroll
  for (int i = 0; i < 16; ++i) {
    int idx = t + i * 256;
    int r = idx >> 6, c = idx & 63;
    tile[r][c] = fast_bf16(src[(size_t)(r0 + r) * 1024 + (c0 + c)]);
  }
  __syncthreads();
#pragma unroll
  for (int i = 0; i < 16; ++i) {
    int idx = t + i * 256;
    int c = idx >> 6, r = idx & 63;
    dst[(size_t)(c0 + c) * 1024 + (r0 + r)] = tile[r][c];
  }
}

// ---------------- 128x128 bf16 GEMM mainloop, XOR-swizzled LDS ----------------
// LDS layout: 16B chunk c of row r stored at chunk position c^(r&7).
// All fragment reads use rows == l15 (mod 8), so reads are conflict-free.
__device__ __forceinline__ void gemm128_mainloop(const bf16* __restrict__ A,
                                                 const bf16* __restrict__ Bt, int K,
                                                 int rowBase, int colBase,
                                                 bf16* As, bf16* Bs,
                                                 f32x4 (&acc)[4][4]) {
  int t = threadIdx.x, lane = t & 63, w = t >> 6;
  int wM = w >> 1, wN = w & 1, quad = lane >> 4, l15 = lane & 15;
  int r_off = lane >> 3;
  int c_sw = (((lane & 7) ^ r_off) << 3);  // swizzled source column (elements)
  int sw = l15 & 7;
  for (int k0 = 0; k0 < K; k0 += 64) {
    __syncthreads();  // previous tile's compute reads done
#pragma unroll
    for (int i = 0; i < 4; ++i) {
      int e = i * 2048 + w * 512;          // wave-uniform LDS segment (elements)
      int row = (e >> 6) + r_off;
      async_ld16(A + (size_t)(rowBase + row) * K + (k0 + c_sw), As + e);
      async_ld16(Bt + (size_t)(colBase + row) * K + (k0 + c_sw), Bs + e);
    }
    __syncthreads();  // drains vmcnt -> staged data visible
#pragma unroll
    for (int ks = 0; ks < 2; ++ks) {
      int co = (((ks * 4 + quad) ^ sw) << 3);
      bf16x8 af[4], bfr[4];
#pragma unroll
      for (int mi = 0; mi < 4; ++mi)
        af[mi] = *(const bf16x8*)(As + (wM * 64 + mi * 16 + l15) * 64 + co);
#pragma unroll
      for (int ni = 0; ni < 4; ++ni)
        bfr[ni] = *(const bf16x8*)(Bs + (wN * 64 + ni * 16 + l15) * 64 + co);
#pragma unroll
      for (int mi = 0; mi < 4; ++mi)
#pragma unroll
        for (int ni = 0; ni < 4; ++ni)
          acc[mi][ni] = __builtin_amdgcn_mfma_f32_16x16x32_bf16(af[mi], bfr[ni], acc[mi][ni], 0, 0, 0);
    }
  }
}

// GEMM1: X[8192,1024] @ Wqkv^T[3072,1024] -> Q [bh][s][d] (scaled by log2e/8),
// K [bh][s][d], V^T [bh][d][s] bf16. All epilogues go through LDS re-tiles so
// global stores are coalesced b128.
__global__ __launch_bounds__(256) void gemm_qkv(const bf16* __restrict__ X,
                                                const bf16* __restrict__ Wt,
                                                const float* __restrict__ bq,
                                                const float* __restrict__ bk,
                                                const float* __restrict__ bv,
                                                bf16* __restrict__ Qo,
                                                bf16* __restrict__ Ko,
                                                bf16* __restrict__ Vto) {
  __shared__ alignas(16) bf16 smem[2 * 128 * 64];  // As|Bs; epilogues reuse
  bf16* As = smem;
  bf16* Bs = smem + 128 * 64;
  f32x4 acc[4][4];
  f32x4 z = {0.f, 0.f, 0.f, 0.f};
#pragma unroll
  for (int mi = 0; mi < 4; ++mi)
#pragma unroll
    for (int ni = 0; ni < 4; ++ni) acc[mi][ni] = z;
  // grid: x = col (24) fast dim -> in-flight window reuses A-tiles across cols in L2
  int rowBase = blockIdx.y * 128, colBase = blockIdx.x * 128;
  gemm128_mainloop(X, Wt, 1024, rowBase, colBase, As, Bs, acc);

  int t = threadIdx.x, lane = t & 63, w = t >> 6;
  int wM = w >> 1, wN = w & 1, quad = lane >> 4, l15 = lane & 15;
  int which = colBase >> 10;  // 0:q 1:k 2:v (128-tiles never straddle)
  int baseh = (colBase & 1023) >> 6;
  int b = rowBase >> 11, s0 = rowBase & 2047;

  if (which == 2) {
    // V^T [bh][d][s]: LDS re-tile per 64-col half, then coalesced b128 stores.
#pragma unroll
    for (int hp = 0; hp < 2; ++hp) {
      __syncthreads();  // smem free (mainloop or previous pass reads done)
      if (wN == hp) {
#pragma unroll
        for (int mi = 0; mi < 4; ++mi)
#pragma unroll
          for (int ni = 0; ni < 4; ++ni) {
            int d = ni * 16 + l15;
            float bb = bv[(colBase & 1023) + hp * 64 + d];
            int sl = wM * 64 + mi * 16 + quad * 4;
            uint2 pv;
            pv.x = pack_bf16(acc[mi][ni][0] + bb, acc[mi][ni][1] + bb);
            pv.y = pack_bf16(acc[mi][ni][2] + bb, acc[mi][ni][3] + bb);
            *(uint2*)(smem + d * 136 + sl) = pv;
          }
      }
      __syncthreads();  // tile [64 d][128 s] staged
      int hg = baseh + hp;
#pragma unroll
      for (int it = 0; it < 4; ++it) {
        int idx = t + it * 256;
        int d = idx >> 4, c = idx & 15;
        bf16x8 vv = *(const bf16x8*)(smem + d * 136 + c * 8);
        *(bf16x8*)(Vto + (((size_t)((b << 4) + hg) << 6) + d) * 2048 + s0 + c * 8) = vv;
      }
    }
  } else {
    // Q/K [bh][s][d]: stage [128 s][64 d] (+pad) per head-half, then each
    // head-half is a CONTIGUOUS 16 KB global region -> perfect b128 stores.
    const float* bias = which == 0 ? bq : bk;
    bf16* dst = which == 0 ? Qo : Ko;
    float scale = which == 0 ? 0.125f * 1.44269504f : 1.0f;
#pragma unroll
    for (int hp = 0; hp < 2; ++hp) {
      __syncthreads();
      if (wN == hp) {
#pragma unroll
        for (int mi = 0; mi < 4; ++mi)
#pragma unroll
          for (int ni = 0; ni < 4; ++ni) {
            int d = ni * 16 + l15;
            float bb = bias[(colBase & 1023) + hp * 64 + d];
            int m = wM * 64 + mi * 16 + quad * 4;
#pragma unroll
            for (int r = 0; r < 4; ++r)
              smem[(m + r) * 72 + d] = fast_bf16((acc[mi][ni][r] + bb) * scale);
          }
      }
      __syncthreads();
      int hg = baseh + hp;
      bf16* gbase = dst + ((((size_t)((b << 4) + hg)) * 2048 + s0) << 6);
#pragma unroll
      for (int it = 0; it < 4; ++it) {
        int idx = t + it * 256;
        int m = idx >> 3, c = idx & 7;
        bf16x8 vv = *(const bf16x8*)(smem + m * 72 + c * 8);
        *(bf16x8*)(gbase + m * 64 + c * 8) = vv;
      }
    }
  }
}

// GEMM2: ctx[8192,1024] @ Wo^T[1024,1024] + bo -> out fp32
__global__ __launch_bounds__(256) void gemm_out(const bf16* __restrict__ Cb,
                                                const bf16* __restrict__ Wot,
                                                const float* __restrict__ bo,
                                                float* __restrict__ out) {
  __shared__ alignas(16) bf16 As[128 * 64];
  __shared__ alignas(16) bf16 Bs[128 * 64];
  f32x4 acc[4][4];
  f32x4 z = {0.f, 0.f, 0.f, 0.f};
#pragma unroll
  for (int mi = 0; mi < 4; ++mi)
#pragma unroll
    for (int ni = 0; ni < 4; ++ni) acc[mi][ni] = z;
  int rowBase = blockIdx.y * 128, colBase = blockIdx.x * 128;
  gemm128_mainloop(Cb, Wot, 1024, rowBase, colBase, As, Bs, acc);

  int t = threadIdx.x, lane = t & 63, w = t >> 6;
  int wM = w >> 1, wN = w & 1, quad = lane >> 4, l15 = lane & 15;
#pragma unroll
  for (int mi = 0; mi < 4; ++mi)
#pragma unroll
    for (int ni = 0; ni < 4; ++ni) {
      int n = colBase + wN * 64 + ni * 16 + l15;
      float bb = bo[n];
#pragma unroll
      for (int r = 0; r < 4; ++r) {
        int m = rowBase + wM * 64 + mi * 16 + quad * 4 + r;
        out[(size_t)m * 1024 + n] = acc[mi][ni][r] + bb;
      }
    }
}

// ---------------- flash attention: 256q blocks, 64q/wave, half-split pipeline ----
// R4 addressing (conflict-free XOR-swizzled P, 64-wide rows) + half-split exp/PV
// overlap + l via ones-B MFMA (sums the rounded P actually used by PV; lands
// per-lane in the exact epilogue layout -> no shuffles/adds).
// Grid (bh=64, q=8): the 8 q-blocks of one bh get consecutive-%8 dispatch ids
// -> same XCD -> K/V L2 reuse.
__global__ __launch_bounds__(256, 2) void attn(const bf16* __restrict__ Q,
                                               const bf16* __restrict__ Kg,
                                               const bf16* __restrict__ Vt,
                                               bf16* __restrict__ ctx) {
  __shared__ alignas(16) bf16 QPs[256 * 64];   // 32 KB: Q stage, then per-wave P
  __shared__ alignas(16) bf16 Ks[2][4096];     // 16 KB [key][dh] swizzled, dbuf
  __shared__ alignas(16) bf16 Vs[2][4096];     // 16 KB [dh][key] swizzled, dbuf

  int t = threadIdx.x, lane = t & 63, w = t >> 6;
  int quad = lane >> 4, l15 = lane & 15;
  int r_off = lane >> 3;
  int c_sw = (((lane & 7) ^ r_off) << 3);
  int sw = l15 & 7;
  int bh = blockIdx.x;
  int q0 = blockIdx.y * 256;
  const bf16* Qp = Q + ((size_t)bh * 2048 + q0) * 64;
  const bf16* Kp = Kg + (size_t)bh * 2048 * 64;
  const bf16* Vp = Vt + (size_t)bh * 64 * 2048;

  // prologue: stage own wave's 64 Q rows + K/V tile 0 into buf 0
#pragma unroll
  for (int i = 0; i < 8; ++i) {
    int e = w * 4096 + i * 512;
    int row = (e >> 6) + r_off;
    async_ld16(Qp + (size_t)row * 64 + c_sw, QPs + e);
  }
#pragma unroll
  for (int i = 0; i < 2; ++i) {
    int e = w * 1024 + i * 512;
    int row = (e >> 6) + r_off;
    async_ld16(Kp + (size_t)row * 64 + c_sw, Ks[0] + e);
    async_ld16(Vp + (size_t)row * 2048 + c_sw, Vs[0] + e);
  }
  __syncthreads();  // drains vmcnt: Q + tile0 ready

  // Q B-fragments: 8 x bf16x8 = 32 VGPRs (own wave's 64 rows)
  bf16x8 qf[2][4];
#pragma unroll
  for (int ks = 0; ks < 2; ++ks)
#pragma unroll
    for (int qi = 0; qi < 4; ++qi)
      qf[ks][qi] = *(const bf16x8*)(QPs + (w * 64 + qi * 16 + l15) * 64 + (((ks * 4 + quad) ^ sw) << 3));
  asm volatile("s_waitcnt lgkmcnt(0)" ::: "memory");  // qf in regs before P overwrites

  bf16* Ps = QPs + w * 4096;  // per-wave 64x64 P buffer == own Q rows (safe overlay)

  bf16 one1 = (bf16)1.0f;
  bf16x8 ones = {one1, one1, one1, one1, one1, one1, one1, one1};

  f32x4 o[4][4];
  f32x4 ol[4];
  f32x4 z = {0.f, 0.f, 0.f, 0.f};
#pragma unroll
  for (int mi = 0; mi < 4; ++mi) {
    ol[mi] = z;
#pragma unroll
    for (int ni = 0; ni < 4; ++ni) o[mi][ni] = z;
  }

  for (int kt = 0; kt < 32; ++kt) {
    int cur = kt & 1;
    // prefetch next K/V tile into the other buffer (overlaps compute below)
    if (kt < 31) {
      int kn = (kt + 1) * 64;
#pragma unroll
      for (int i = 0; i < 2; ++i) {
        int e = w * 1024 + i * 512;
        int row = (e >> 6) + r_off;
        async_ld16(Kp + (size_t)(kn + row) * 64 + c_sw, Ks[cur ^ 1] + e);
        async_ld16(Vp + (size_t)row * 2048 + kn + c_sw, Vs[cur ^ 1] + e);
      }
    }
    const bf16* Kc = Ks[cur];
    const bf16* Vc = Vs[cur];

    // ---- S^T keys 0..31 (ki=0,1) ----
    f32x4 sA[2][4];
#pragma unroll
    for (int ki = 0; ki < 2; ++ki)
#pragma unroll
      for (int qi = 0; qi < 4; ++qi) sA[ki][qi] = z;
#pragma unroll
    for (int ks = 0; ks < 2; ++ks) {
      int co = (((ks * 4 + quad) ^ sw) << 3);
      bf16x8 kf0 = *(const bf16x8*)(Kc + (l15) * 64 + co);
      bf16x8 kf1 = *(const bf16x8*)(Kc + (16 + l15) * 64 + co);
#pragma unroll
      for (int qi = 0; qi < 4; ++qi) {
        sA[0][qi] = __builtin_amdgcn_mfma_f32_16x16x32_bf16(kf0, qf[ks][qi], sA[0][qi], 0, 0, 0);
        sA[1][qi] = __builtin_amdgcn_mfma_f32_16x16x32_bf16(kf1, qf[ks][qi], sA[1][qi], 0, 0, 0);
      }
    }
    // exp + pack + write P half A (logical chunks 0..3, R4 swizzle)
#pragma unroll
    for (int qi = 0; qi < 4; ++qi)
#pragma unroll
      for (int ki = 0; ki < 2; ++ki) {
        float p0 = __builtin_amdgcn_exp2f(sA[ki][qi][0]);
        float p1 = __builtin_amdgcn_exp2f(sA[ki][qi][1]);
        float p2 = __builtin_amdgcn_exp2f(sA[ki][qi][2]);
        float p3 = __builtin_amdgcn_exp2f(sA[ki][qi][3]);
        uint2 pb;
        pb.x = pack_bf16(p0, p1);
        pb.y = pack_bf16(p2, p3);
        int cs = (ki * 2 + (quad >> 1)) ^ sw;
        *(uint2*)(Ps + (qi * 16 + l15) * 64 + cs * 8 + (quad & 1) * 4) = pb;
      }

    // ---- S^T keys 32..63 (ki=2,3) ----
    f32x4 sB[2][4];
#pragma unroll
    for (int ki = 0; ki < 2; ++ki)
#pragma unroll
      for (int qi = 0; qi < 4; ++qi) sB[ki][qi] = z;
#pragma unroll
    for (int ks = 0; ks < 2; ++ks) {
      int co = (((ks * 4 + quad) ^ sw) << 3);
      bf16x8 kf2 = *(const bf16x8*)(Kc + (32 + l15) * 64 + co);
      bf16x8 kf3 = *(const bf16x8*)(Kc + (48 + l15) * 64 + co);
#pragma unroll
      for (int qi = 0; qi < 4; ++qi) {
        sB[0][qi] = __builtin_amdgcn_mfma_f32_16x16x32_bf16(kf2, qf[ks][qi], sB[0][qi], 0, 0, 0);
        sB[1][qi] = __builtin_amdgcn_mfma_f32_16x16x32_bf16(kf3, qf[ks][qi], sB[1][qi], 0, 0, 0);
      }
    }

    asm volatile("s_waitcnt lgkmcnt(0)" ::: "memory");  // P half A visible

    // ---- PV half A (keys 0..31, ks=0) + l row-sum ----
    {
      int co = ((quad ^ sw) << 3);
      bf16x8 pf[4], vf[4];
#pragma unroll
      for (int mi = 0; mi < 4; ++mi)
        pf[mi] = *(const bf16x8*)(Ps + (mi * 16 + l15) * 64 + co);
#pragma unroll
      for (int ni = 0; ni < 4; ++ni)
        vf[ni] = *(const bf16x8*)(Vc + (ni * 16 + l15) * 64 + co);
#pragma unroll
      for (int mi = 0; mi < 4; ++mi) {
#pragma unroll
        for (int ni = 0; ni < 4; ++ni)
          o[mi][ni] = __builtin_amdgcn_mfma_f32_16x16x32_bf16(pf[mi], vf[ni], o[mi][ni], 0, 0, 0);
        ol[mi] = __builtin_amdgcn_mfma_f32_16x16x32_bf16(pf[mi], ones, ol[mi], 0, 0, 0);
      }
    }

    // exp + pack + write P half B (logical chunks 4..7) — overlaps PV-A MFMAs
#pragma unroll
    for (int qi = 0; qi < 4; ++qi)
#pragma unroll
      for (int ki = 0; ki < 2; ++ki) {
        float p0 = __builtin_amdgcn_exp2f(sB[ki][qi][0]);
        float p1 = __builtin_amdgcn_exp2f(sB[ki][qi][1]);
        float p2 = __builtin_amdgcn_exp2f(sB[ki][qi][2]);
        float p3 = __builtin_amdgcn_exp2f(sB[ki][qi][3]);
        uint2 pb;
        pb.x = pack_bf16(p0, p1);
        pb.y = pack_bf16(p2, p3);
        int cs = (ki * 2 + 4 + (quad >> 1)) ^ sw;
        *(uint2*)(Ps + (qi * 16 + l15) * 64 + cs * 8 + (quad & 1) * 4) = pb;
      }

    asm volatile("s_waitcnt lgkmcnt(0)" ::: "memory");  // P half B visible

    // ---- PV half B (keys 32..63, ks=1) + l row-sum ----
    {
      int co = (((4 + quad) ^ sw) << 3);
      bf16x8 pf[4], vf[4];
#pragma unroll
      for (int mi = 0; mi < 4; ++mi)
        pf[mi] = *(const bf16x8*)(Ps + (mi * 16 + l15) * 64 + co);
#pragma unroll
      for (int ni = 0; ni < 4; ++ni)
        vf[ni] = *(const bf16x8*)(Vc + (ni * 16 + l15) * 64 + co);
#pragma unroll
      for (int mi = 0; mi < 4; ++mi) {
#pragma unroll
        for (int ni = 0; ni < 4; ++ni)
          o[mi][ni] = __builtin_amdgcn_mfma_f32_16x16x32_bf16(pf[mi], vf[ni], o[mi][ni], 0, 0, 0);
        ol[mi] = __builtin_amdgcn_mfma_f32_16x16x32_bf16(pf[mi], ones, ol[mi], 0, 0, 0);
      }
    }

    // end-of-tile barrier: all waves done with buf[cur]; vmcnt(0) drain lands
    // after a full compute phase -> prefetch latency hidden.
    __syncthreads();
  }

  // epilogue: ol[mi][r] = l for query mi*16+quad*4+r (uniform across l15)
  int b = bh >> 4, h = bh & 15;
#pragma unroll
  for (int mi = 0; mi < 4; ++mi) {
    float rl[4];
#pragma unroll
    for (int r = 0; r < 4; ++r) rl[r] = 1.0f / ol[mi][r];
#pragma unroll
    for (int ni = 0; ni < 4; ++ni) {
      int col = h * 64 + ni * 16 + l15;
#pragma unroll
      for (int r = 0; r < 4; ++r) {
        int q = q0 + w * 64 + mi * 16 + quad * 4 + r;
        ctx[(size_t)(b * 2048 + q) * 1024 + col] = fast_bf16(o[mi][ni][r] * rl[r]);
      }
    }
  }
}

extern "C" void kernel_launch(void* const* d_in, const int* in_sizes, int n_in,
                              void* d_out, int out_size, void* d_ws, size_t ws_size,
                              hipStream_t stream) {
  const float* x  = (const float*)d_in[0];
  const float* Wq = (const float*)d_in[1];
  const float* bq = (const float*)d_in[2];
  const float* Wk = (const float*)d_in[3];
  const float* bk = (const float*)d_in[4];
  const float* Wv = (const float*)d_in[5];
  const float* bv = (const float*)d_in[6];
  const float* Wo = (const float*)d_in[7];
  const float* bo = (const float*)d_in[8];
  float* out = (float*)d_out;

  char* ws = (char*)d_ws;
  const size_t MB = 1048576;
  bf16* xb  = (bf16*)(ws);             // 16 MB: x bf16 [8192][1024]
  bf16* Wt  = (bf16*)(ws + 16 * MB);   //  6 MB: Wqkv^T [3072][1024]
  bf16* Wot = (bf16*)(ws + 22 * MB);   //  2 MB: Wo^T   [1024][1024]
  bf16* Qb  = (bf16*)(ws + 24 * MB);   // 16 MB: Q [64][2048][64] (pre-scaled by log2e/8)
  bf16* Kb  = (bf16*)(ws + 40 * MB);   // 16 MB: K [64][2048][64]
  bf16* Vtb = (bf16*)(ws + 56 * MB);   // 16 MB: V^T [64][64][2048]
  bf16* Cx  = (bf16*)(ws + 72 * MB);   // 16 MB: ctx [8192][1024]

  cast_f32_bf16<<<8192, 256, 0, stream>>>(x, xb, 8388608);
  transpose_weights<<<dim3(16, 16, 4), 256, 0, stream>>>(Wq, Wk, Wv, Wo, Wt, Wot);
  gemm_qkv<<<dim3(24, 64, 1), 256, 0, stream>>>(xb, Wt, bq, bk, bv, Qb, Kb, Vtb);
  attn<<<dim3(64, 8, 1), 256, 0, stream>>>(Qb, Kb, Vtb, Cx);
  gemm_out<<<dim3(8, 64, 1), 256, 0, stream>>>(Cx, Wot, bo, out);
}